// Round 16
// baseline (221.866 us; speedup 1.0000x reference)
//
#include <hip/hip_runtime.h>
#include <hip/hip_bf16.h>

#define E_NUM 64
#define IN_SZ 512
#define OUT_SZ 512
#define N_TOK 131072
#define CAP 3072

#define BM 256
#define BN 256
#define BK 64
#define THREADS 512
#define RT_MAX 12   // CAP/BM
#define CT_NUM 2    // OUT/BN
#define JT 8        // IN_SZ/BK
#define NWG (E_NUM * RT_MAX * CT_NUM)   // 1536

typedef __attribute__((ext_vector_type(8))) short short8;
typedef __attribute__((ext_vector_type(4))) float f32x4;

__device__ inline unsigned short f2bf(float f) {
    unsigned int u = __float_as_uint(f);
    unsigned int r = (u + 0x7FFF + ((u >> 16) & 1)) >> 16;
    return (unsigned short)r;
}

// packed fp32x2 -> bf16x2 (RNE), single HW instr on gfx950
__device__ inline unsigned int cvtpk(float a, float b) {
    unsigned int r;
    asm("v_cvt_pk_bf16_f32 %0, %1, %2" : "=v"(r) : "v"(a), "v"(b));
    return r;
}

#define GLOAD_LDS16(g, l)                                                     \
    __builtin_amdgcn_global_load_lds(                                         \
        (const __attribute__((address_space(1))) void*)(g),                   \
        (__attribute__((address_space(3))) void*)(l), 16, 0, 0)

// ---------------- kernel 1: exclusive prefix sum of expert sizes ----------
__global__ void offsets_kernel(const int* __restrict__ sizes, int* __restrict__ offs) {
    int e = threadIdx.x;
    int s = 0;
    for (int i = 0; i < e; ++i) s += sizes[i];
    offs[e] = s;
}

// ---------------- kernel 2: W [E][K][N] f32 -> WT [E][N][K] bf16 ----------
__global__ __launch_bounds__(256) void prep_wt(const float* __restrict__ W,
                                               unsigned short* __restrict__ WT) {
    __shared__ float t[32][33];
    int k0 = blockIdx.x * 32, n0 = blockIdx.y * 32, e = blockIdx.z;
    const float* We = W + (size_t)e * IN_SZ * OUT_SZ;
    int tid = threadIdx.x;
    int r = tid >> 3, c4 = (tid & 7) * 4;
    float4 v = *(const float4*)(We + (size_t)(k0 + r) * OUT_SZ + n0 + c4);
    t[r][c4 + 0] = v.x; t[r][c4 + 1] = v.y; t[r][c4 + 2] = v.z; t[r][c4 + 3] = v.w;
    __syncthreads();
    ushort4 o;
    o.x = f2bf(t[c4 + 0][r]);
    o.y = f2bf(t[c4 + 1][r]);
    o.z = f2bf(t[c4 + 2][r]);
    o.w = f2bf(t[c4 + 3][r]);
    unsigned short* O = WT + (size_t)e * IN_SZ * OUT_SZ + (size_t)(n0 + r) * IN_SZ + k0 + c4;
    *(ushort4*)O = o;
}

// ---------------- kernel 3: 256x256 BK=64 8-PHASE grouped GEMM ------------
// R15 (2-phase, 167us) + the T3+T4 schedule (m248v2: 8ph = +10..27% on
// grouped GEMM). Same verified swizzle + fragment addressing as R15; ONLY
// the schedule changes. Per K-tile: 4 phases (ks,mh), each
//   {ds_read subtile || issue stage ops -> s_barrier -> setprio+16 MFMA
//    -> s_barrier}.
// A fp32->regs issued p0-p1; B(t+2) gload_lds issued p2-p3 (AFTER last A
// load so writeA's implicit wait = vmcnt(4), B stays in flight). B 3-buf
// (t%3): tile-end wait = vmcnt(4) -- NEVER 0 in steady state; B loads span
// a full tile (~2000cy > HBM latency). A(t+1) ds_writes drained by explicit
// lgkmcnt(0) before the tile-final barrier. LDS = 2x32K(A) + 3x32K(B) =
// 160 KB (hw max; 144K static verified in R6).
__global__ __launch_bounds__(THREADS, 2) void gemm_moe(
    const float* __restrict__ A, const int* __restrict__ sizes,
    const unsigned short* __restrict__ WT, const int* __restrict__ offs,
    float* __restrict__ out)
{
    // bijective XCD swizzle: 1536 blocks, 192 per XCD chunk
    int b0 = blockIdx.x;
    int wg = (b0 & 7) * (NWG / 8) + (b0 >> 3);
    int ct = wg & (CT_NUM - 1);
    int rt = (wg >> 1) % RT_MAX;
    int e  = wg / (RT_MAX * CT_NUM);

    int size_e = sizes[e];
    int rows0 = rt * BM;
    if (rows0 >= size_e) return;
    int off_e = offs[e];
    int rows_rem = size_e - rows0;                      // >= 1
    int maxr = (rows_rem < BM ? rows_rem : BM) - 1;

    __shared__ unsigned short lsA[2][BM * BK];   // 2 x 32 KB
    __shared__ unsigned short lsB[3][BN * BK];   // 3 x 32 KB -> 160 KB

    int tid = threadIdx.x, l = tid & 63, w = tid >> 6;   // w in 0..7
    const char* WTe = (const char*)(WT + (size_t)e * IN_SZ * OUT_SZ);
    const float* Abase = A + (size_t)(off_e + rows0) * IN_SZ;

    // ---- A staging geometry (R15-verified): unit u = tid + 512*jj ->
    //      LDS row u>>3, slot u&7 holds global k-chunk c = slot^(row&7).
    int aoff[4];
    #pragma unroll
    for (int jj = 0; jj < 4; ++jj) {
        int u = tid + THREADS * jj;
        int row = u >> 3, s = u & 7;
        int c = s ^ (row & 7);
        int gr = row <= maxr ? row : maxr;
        aoff[jj] = gr * IN_SZ + c * 8;
    }
    // ---- B staging geometry (R15-verified) ----
    int boff[4];
    #pragma unroll
    for (int i = 0; i < 4; ++i) {
        int unit = (w * 4 + i) * 64 + l;
        int row = unit >> 3, s = unit & 7;
        int c = s ^ (row & 7);
        boff[i] = (ct * BN + row) * (IN_SZ * 2) + c * 16;
    }

    f32x4 ar[8];            // single in-flight A register set (32 VGPR)

    auto loadA_h = [&](int kt, int h) {      // h=0: jj 0,1 ; h=1: jj 2,3
        #pragma unroll
        for (int jj = 2 * h; jj < 2 * h + 2; ++jj) {
            ar[2 * jj]     = *(const f32x4*)(Abase + aoff[jj] + kt * BK);
            ar[2 * jj + 1] = *(const f32x4*)(Abase + aoff[jj] + kt * BK + 4);
        }
    };
    auto writeA = [&](int buf) {
        #pragma unroll
        for (int jj = 0; jj < 4; ++jj) {
            unsigned int p0 = cvtpk(ar[2 * jj][0], ar[2 * jj][1]);
            unsigned int p1 = cvtpk(ar[2 * jj][2], ar[2 * jj][3]);
            unsigned int p2 = cvtpk(ar[2 * jj + 1][0], ar[2 * jj + 1][1]);
            unsigned int p3 = cvtpk(ar[2 * jj + 1][2], ar[2 * jj + 1][3]);
            uint4 pk = make_uint4(p0, p1, p2, p3);
            *(uint4*)((char*)&lsA[buf][0] + (tid + THREADS * jj) * 16) = pk;
        }
    };
    auto stageB_h = [&](int buf, int kt, int h) {   // 2 gloads per call
        #pragma unroll
        for (int i = 2 * h; i < 2 * h + 2; ++i)
            GLOAD_LDS16(WTe + boff[i] + kt * 128, &lsB[buf][(w * 4 + i) * 512]);
    };

    int wm = (w >> 2) * 128, wn = (w & 3) * 64;  // 2M x 4N, wave tile 128x64
    int lrow = l & 15, kq = l >> 4;
    int abm[8], bbn[4];
    #pragma unroll
    for (int mm = 0; mm < 8; ++mm) abm[mm] = (wm + mm * 16 + lrow) * 128;
    #pragma unroll
    for (int nn = 0; nn < 4; ++nn) bbn[nn] = (wn + nn * 16 + lrow) * 128;
    int sk0 = ((0 * 4 + kq) ^ (lrow & 7)) * 16;   // ks=0 slot byte
    int sk1 = ((1 * 4 + kq) ^ (lrow & 7)) * 16;   // ks=1 slot byte

    f32x4 acc[8][4] = {};

    #define RD_A(mh, sk)                                                      \
        _Pragma("unroll")                                                     \
        for (int i = 0; i < 4; ++i)                                           \
            af[i] = *(const short8*)(pA + abm[(mh) * 4 + i] + (sk));
    #define RD_B(sk)                                                          \
        _Pragma("unroll")                                                     \
        for (int n = 0; n < 4; ++n)                                           \
            bfr[n] = *(const short8*)(pB + bbn[n] + (sk));
    #define MFMA16(mh)                                                        \
        __builtin_amdgcn_s_setprio(1);                                        \
        _Pragma("unroll")                                                     \
        for (int i = 0; i < 4; ++i)                                           \
            _Pragma("unroll")                                                 \
            for (int n = 0; n < 4; ++n)                                       \
                acc[(mh) * 4 + i][n] = __builtin_amdgcn_mfma_f32_16x16x32_bf16(\
                    af[i], bfr[n], acc[(mh) * 4 + i][n], 0, 0, 0);            \
        __builtin_amdgcn_s_setprio(0);

    // ---- prologue: A(0)->regs, B(0),B(1)->LDS, A(0)->LDS ----
    loadA_h(0, 0); loadA_h(0, 1);            // 8 A ops (oldest)
    stageB_h(0, 0, 0); stageB_h(0, 0, 1);    // B(0): 4 gloads
    stageB_h(1, 1, 0); stageB_h(1, 1, 1);    // B(1): 4 gloads
    writeA(0);                               // implicit wait: A done, 8 B fly
    asm volatile("s_waitcnt vmcnt(4)" ::: "memory");   // B(0) landed, B(1) fly
    __builtin_amdgcn_sched_barrier(0);
    asm volatile("s_waitcnt lgkmcnt(0)" ::: "memory"); // A(0) writes drained
    __builtin_amdgcn_sched_barrier(0);
    __builtin_amdgcn_s_barrier();
    __builtin_amdgcn_sched_barrier(0);

    // ---- main loop: 8 K-tiles x 4 phases ----
    #pragma unroll
    for (int t = 0; t < JT; ++t) {
        const char* pA = (const char*)&lsA[t & 1][0];
        const char* pB = (const char*)&lsB[t % 3][0];
        short8 af[4], bfr[4];

        // phase 0: ks=0, mh=0   (+ first half of A(t+1) loads)
        RD_A(0, sk0); RD_B(sk0);
        if (t + 1 < JT) loadA_h(t + 1, 0);
        __builtin_amdgcn_s_barrier();
        MFMA16(0);
        __builtin_amdgcn_s_barrier();

        // phase 1: ks=0, mh=1   (+ second half of A(t+1) loads)
        RD_A(1, sk0);
        if (t + 1 < JT) loadA_h(t + 1, 1);
        __builtin_amdgcn_s_barrier();
        MFMA16(1);
        __builtin_amdgcn_s_barrier();

        // phase 2: ks=1, mh=0   (+ B(t+2) gloads, issued AFTER all A loads)
        RD_A(0, sk1); RD_B(sk1);
        if (t + 2 < JT) stageB_h((t + 2) % 3, t + 2, 0);
        __builtin_amdgcn_s_barrier();
        MFMA16(0);
        __builtin_amdgcn_s_barrier();

        // phase 3: ks=1, mh=1   (+ rest of B(t+2), A(t+1) cvt+ds_write)
        RD_A(1, sk1);
        if (t + 2 < JT) stageB_h((t + 2) % 3, t + 2, 1);
        if (t + 1 < JT) writeA((t + 1) & 1);  // implicit vmcnt(4): B(t+2) fly
        __builtin_amdgcn_s_barrier();
        MFMA16(1);
        // tile boundary: drain B(t+1) (FIFO: older than the 4 in-flight
        // B(t+2)) + own A ds_writes; keep B(t+2) flying across the barrier.
        if (t < JT - 1) {
            if (t + 2 < JT) {
                asm volatile("s_waitcnt vmcnt(4)" ::: "memory");
            } else {
                asm volatile("s_waitcnt vmcnt(0)" ::: "memory");
            }
            __builtin_amdgcn_sched_barrier(0);
            asm volatile("s_waitcnt lgkmcnt(0)" ::: "memory");
            __builtin_amdgcn_sched_barrier(0);
            __builtin_amdgcn_s_barrier();
            __builtin_amdgcn_sched_barrier(0);
        }
    }

    // epilogue: C/D layout col = lane&15, row = (lane>>4)*4 + reg
    float* outb = out + (size_t)(off_e + rows0) * OUT_SZ + ct * BN + wn;
    #pragma unroll
    for (int mm = 0; mm < 8; ++mm) {
        #pragma unroll
        for (int jj = 0; jj < 4; ++jj) {
            int rl = wm + mm * 16 + kq * 4 + jj;
            if (rl < rows_rem) {
                float* po = outb + (size_t)rl * OUT_SZ + lrow;
                #pragma unroll
                for (int nn = 0; nn < 4; ++nn)
                    po[nn * 16] = acc[mm][nn][jj];
            }
        }
    }
}

extern "C" void kernel_launch(void* const* d_in, const int* in_sizes, int n_in,
                              void* d_out, int out_size, void* d_ws, size_t ws_size,
                              hipStream_t stream) {
    const float* A      = (const float*)d_in[0];
    const int* sizes    = (const int*)d_in[1];
    const float* W      = (const float*)d_in[2];
    float* out          = (float*)d_out;

    unsigned short* WT  = (unsigned short*)d_ws;                       // 32 MB
    int* offs           = (int*)((char*)d_ws + (size_t)E_NUM * IN_SZ * OUT_SZ * 2);

    offsets_kernel<<<1, E_NUM, 0, stream>>>(sizes, offs);
    prep_wt<<<dim3(IN_SZ / 32, OUT_SZ / 32, E_NUM), 256, 0, stream>>>(W, WT);
    gemm_moe<<<NWG, THREADS, 0, stream>>>(A, sizes, WT, offs, out);
}

// Round 17
// 184.292 us; speedup vs baseline: 1.2039x; 1.2039x over previous
//
#include <hip/hip_runtime.h>
#include <hip/hip_bf16.h>

#define E_NUM 64
#define IN_SZ 512
#define OUT_SZ 512
#define N_TOK 131072
#define CAP 3072

#define BM 256
#define BN 256
#define BK 64
#define THREADS 512
#define RT_MAX 12   // CAP/BM
#define CT_NUM 2    // OUT/BN
#define JT 8        // IN_SZ/BK
#define NWG (E_NUM * RT_MAX * CT_NUM)   // 1536

typedef __attribute__((ext_vector_type(8))) short short8;
typedef __attribute__((ext_vector_type(4))) float f32x4;

__device__ inline unsigned short f2bf(float f) {
    unsigned int u = __float_as_uint(f);
    unsigned int r = (u + 0x7FFF + ((u >> 16) & 1)) >> 16;
    return (unsigned short)r;
}

// packed fp32x2 -> bf16x2 (RNE), single HW instr on gfx950
__device__ inline unsigned int cvtpk(float a, float b) {
    unsigned int r;
    asm("v_cvt_pk_bf16_f32 %0, %1, %2" : "=v"(r) : "v"(a), "v"(b));
    return r;
}

#define GLOAD_LDS16(g, l)                                                     \
    __builtin_amdgcn_global_load_lds(                                         \
        (const __attribute__((address_space(1))) void*)(g),                   \
        (__attribute__((address_space(3))) void*)(l), 16, 0, 0)

// ---------------- kernel 1: exclusive prefix sum of expert sizes ----------
__global__ void offsets_kernel(const int* __restrict__ sizes, int* __restrict__ offs) {
    int e = threadIdx.x;
    int s = 0;
    for (int i = 0; i < e; ++i) s += sizes[i];
    offs[e] = s;
}

// ---------------- kernel 2: W [E][K][N] f32 -> WT [E][N][K] bf16 ----------
__global__ __launch_bounds__(256) void prep_wt(const float* __restrict__ W,
                                               unsigned short* __restrict__ WT) {
    __shared__ float t[32][33];
    int k0 = blockIdx.x * 32, n0 = blockIdx.y * 32, e = blockIdx.z;
    const float* We = W + (size_t)e * IN_SZ * OUT_SZ;
    int tid = threadIdx.x;
    int r = tid >> 3, c4 = (tid & 7) * 4;
    float4 v = *(const float4*)(We + (size_t)(k0 + r) * OUT_SZ + n0 + c4);
    t[r][c4 + 0] = v.x; t[r][c4 + 1] = v.y; t[r][c4 + 2] = v.z; t[r][c4 + 3] = v.w;
    __syncthreads();
    ushort4 o;
    o.x = f2bf(t[c4 + 0][r]);
    o.y = f2bf(t[c4 + 1][r]);
    o.z = f2bf(t[c4 + 2][r]);
    o.w = f2bf(t[c4 + 3][r]);
    unsigned short* O = WT + (size_t)e * IN_SZ * OUT_SZ + (size_t)(n0 + r) * IN_SZ + k0 + c4;
    *(ushort4*)O = o;
}

// ---------------- kernel 3: 256x256 BK=64 2-phase grouped GEMM ------------
// SESSION BEST (R15: gemm 167.5us steady, 184.6us total). 8 waves (2M x 4N),
// wave tile 128x64, acc[8][4]=128 regs; lb(512,2); VGPR_Count=128, no spill.
// LDS 128 KB: A bf16 [256][64] 32K + B 32K, double-buffered; 1 block/CU.
// A: reg-staged fp32 (8 dwordx4/thread, issued a full compute early) ->
//    16 cvtpk -> 4 ds_write_b128. B: 4 global_load_lds(16B)/wave.
// Swizzle (128 B rows = 8 x 16B slots): data chunk c lives at slot
// s = c ^ (row&7); 0 measured bank conflicts. B involution via pre-swizzled
// global source (rule #21). XCD-bijective block chunking (1536 % 8 == 0).
// R16 lesson: 8-phase barriers at 1 block/CU convoy -> keep 2-phase.
__global__ __launch_bounds__(THREADS, 2) void gemm_moe(
    const float* __restrict__ A, const int* __restrict__ sizes,
    const unsigned short* __restrict__ WT, const int* __restrict__ offs,
    float* __restrict__ out)
{
    // bijective XCD swizzle: 1536 blocks, 192 per XCD chunk
    int b0 = blockIdx.x;
    int wg = (b0 & 7) * (NWG / 8) + (b0 >> 3);
    int ct = wg & (CT_NUM - 1);
    int rt = (wg >> 1) % RT_MAX;
    int e  = wg / (RT_MAX * CT_NUM);

    int size_e = sizes[e];
    int rows0 = rt * BM;
    if (rows0 >= size_e) return;
    int off_e = offs[e];
    int rows_rem = size_e - rows0;                      // >= 1
    int maxr = (rows_rem < BM ? rows_rem : BM) - 1;

    __shared__ unsigned short lsA[2][BM * BK];   // 2 x 32 KB
    __shared__ unsigned short lsB[2][BN * BK];   // 2 x 32 KB -> 128 KB

    int tid = threadIdx.x, l = tid & 63, w = tid >> 6;   // w in 0..7
    const char* WTe = (const char*)(WT + (size_t)e * IN_SZ * OUT_SZ);
    const float* Abase = A + (size_t)(off_e + rows0) * IN_SZ;

    // ---- A staging geometry: 2048 16B-units; thread owns u = tid + 512*jj.
    // unit u -> LDS row u>>3, slot u&7; holds global k-chunk c = s^(row&7).
    int aoff[4];            // fp32 element offset of the unit's global data
    #pragma unroll
    for (int jj = 0; jj < 4; ++jj) {
        int u = tid + THREADS * jj;
        int row = u >> 3, s = u & 7;
        int c = s ^ (row & 7);
        int gr = row <= maxr ? row : maxr;
        aoff[jj] = gr * IN_SZ + c * 8;
    }
    // ---- B staging: 4 gload calls/wave; call i dest units (w*4+i)*64 + l.
    int boff[4];            // byte offset within WTe (minus kt term)
    #pragma unroll
    for (int i = 0; i < 4; ++i) {
        int unit = (w * 4 + i) * 64 + l;
        int row = unit >> 3, s = unit & 7;
        int c = s ^ (row & 7);
        boff[i] = (ct * BN + row) * (IN_SZ * 2) + c * 16;
    }

    f32x4 ar[8];            // single in-flight A register set (32 VGPR)

    auto loadA = [&](int kt) {
        #pragma unroll
        for (int jj = 0; jj < 4; ++jj) {
            ar[2 * jj]     = *(const f32x4*)(Abase + aoff[jj] + kt * BK);
            ar[2 * jj + 1] = *(const f32x4*)(Abase + aoff[jj] + kt * BK + 4);
        }
    };
    auto writeA = [&](int buf) {
        #pragma unroll
        for (int jj = 0; jj < 4; ++jj) {
            unsigned int p0 = cvtpk(ar[2 * jj][0], ar[2 * jj][1]);
            unsigned int p1 = cvtpk(ar[2 * jj][2], ar[2 * jj][3]);
            unsigned int p2 = cvtpk(ar[2 * jj + 1][0], ar[2 * jj + 1][1]);
            unsigned int p3 = cvtpk(ar[2 * jj + 1][2], ar[2 * jj + 1][3]);
            uint4 pk = make_uint4(p0, p1, p2, p3);
            *(uint4*)((char*)&lsA[buf][0] + (tid + THREADS * jj) * 16) = pk;
        }
    };
    auto stageB = [&](int buf, int kt) {
        #pragma unroll
        for (int i = 0; i < 4; ++i)
            GLOAD_LDS16(WTe + boff[i] + kt * 128, &lsB[buf][(w * 4 + i) * 512]);
    };

    int wm = (w >> 2) * 128, wn = (w & 3) * 64;  // 2M x 4N, wave tile 128x64
    int lrow = l & 15, kq = l >> 4;
    int abm[8], bbn[4];
    #pragma unroll
    for (int mm = 0; mm < 8; ++mm) abm[mm] = (wm + mm * 16 + lrow) * 128;
    #pragma unroll
    for (int nn = 0; nn < 4; ++nn) bbn[nn] = (wn + nn * 16 + lrow) * 128;
    int sk0 = ((0 * 4 + kq) ^ (lrow & 7)) * 16;   // ks=0 slot byte
    int sk1 = ((1 * 4 + kq) ^ (lrow & 7)) * 16;   // ks=1 slot byte

    f32x4 acc[8][4] = {};

    // ---- prologue: tile 0 staged ----
    loadA(0); stageB(0, 0);
    writeA(0);                 // compiler waits A0 loads only
    __syncthreads();           // drains B0 DMA + A0 ds_writes

    // ---- main loop: 8 iterations, one barrier each ----
    #pragma unroll
    for (int j = 0; j < JT; ++j) {
        int cur = j & 1;
        if (j + 1 < JT) {
            loadA(j + 1);            // fp32 A -> regs (MFMA-phase of slack)
            stageB(cur ^ 1, j + 1);  // B DMA -> other buffer
        }
        {
            const char* pA = (const char*)&lsA[cur][0];
            const char* pB = (const char*)&lsB[cur][0];
            __builtin_amdgcn_s_setprio(1);
            #pragma unroll
            for (int ks = 0; ks < 2; ++ks) {
                int sk = ks ? sk1 : sk0;
                short8 bfr[4];
                #pragma unroll
                for (int nn = 0; nn < 4; ++nn)
                    bfr[nn] = *(const short8*)(pB + bbn[nn] + sk);
                #pragma unroll
                for (int mm = 0; mm < 8; ++mm) {
                    short8 af = *(const short8*)(pA + abm[mm] + sk);
                    #pragma unroll
                    for (int nn = 0; nn < 4; ++nn)
                        acc[mm][nn] = __builtin_amdgcn_mfma_f32_16x16x32_bf16(
                            af, bfr[nn], acc[mm][nn], 0, 0, 0);
                }
            }
            __builtin_amdgcn_s_setprio(0);
        }
        if (j + 1 < JT)
            writeA(cur ^ 1);         // cvt+ds_write; loads had full MFMA slack
        if (j < JT - 1)
            __syncthreads();
    }

    // epilogue: C/D layout col = lane&15, row = (lane>>4)*4 + reg
    float* outb = out + (size_t)(off_e + rows0) * OUT_SZ + ct * BN + wn;
    #pragma unroll
    for (int mm = 0; mm < 8; ++mm) {
        #pragma unroll
        for (int jj = 0; jj < 4; ++jj) {
            int rl = wm + mm * 16 + kq * 4 + jj;
            if (rl < rows_rem) {
                float* po = outb + (size_t)rl * OUT_SZ + lrow;
                #pragma unroll
                for (int nn = 0; nn < 4; ++nn)
                    po[nn * 16] = acc[mm][nn][jj];
            }
        }
    }
}

extern "C" void kernel_launch(void* const* d_in, const int* in_sizes, int n_in,
                              void* d_out, int out_size, void* d_ws, size_t ws_size,
                              hipStream_t stream) {
    const float* A      = (const float*)d_in[0];
    const int* sizes    = (const int*)d_in[1];
    const float* W      = (const float*)d_in[2];
    float* out          = (float*)d_out;

    unsigned short* WT  = (unsigned short*)d_ws;                       // 32 MB
    int* offs           = (int*)((char*)d_ws + (size_t)E_NUM * IN_SZ * OUT_SZ * 2);

    offsets_kernel<<<1, E_NUM, 0, stream>>>(sizes, offs);
    prep_wt<<<dim3(IN_SZ / 32, OUT_SZ / 32, E_NUM), 256, 0, stream>>>(W, WT);
    gemm_moe<<<NWG, THREADS, 0, stream>>>(A, sizes, WT, offs, out);
}